// Round 14
// baseline (225.525 us; speedup 1.0000x reference)
//
#include <hip/hip_runtime.h>
#include <math.h>

constexpr int BB = 2;
constexpr int SS = 2048;
constexpr int DM = 1024;
constexpr int NH = 16;
constexpr int KD = 64;
constexpr int OUT_ELEMS  = BB*SS*DM;     // 4194304 fp32 (output 0 region)
constexpr int PRES_HALF  = BB*NH*SS*KD;  // 4194304 fp32 (k or v)
#define NEGSENT (-1e30f)

typedef __attribute__((ext_vector_type(8))) short short8;   // 8 x bf16 bits
typedef __attribute__((ext_vector_type(4))) short short4v;  // 4 x bf16 bits
typedef __attribute__((ext_vector_type(4))) float f32x4;

__device__ __forceinline__ float us2f(unsigned short u) {
  union { unsigned int ui; float f; } c; c.ui = ((unsigned int)u) << 16; return c.f;
}
__device__ __forceinline__ short f2s(float f) {
  // round-to-nearest-even bf16 (finite inputs only) — software path
  union { float f; unsigned int u; } c; c.f = f;
  return (short)((c.u + 0x7FFFu + ((c.u >> 16) & 1u)) >> 16);
}
__device__ __forceinline__ short f2s_hw(float f) {
  // hardware RNE bf16 via v_cvt_pk_bf16_f32 (no builtin on gfx950 — T12).
  unsigned int r;
  asm("v_cvt_pk_bf16_f32 %0, %1, %1" : "=v"(r) : "v"(f));
  return (short)r;
}
__device__ __forceinline__ unsigned int pk2(float lo, float hi) {
  // [bf16(lo) | bf16(hi)<<16] in one instruction (S0->low, S1->high)
  unsigned int r;
  asm("v_cvt_pk_bf16_f32 %0, %1, %2" : "=v"(r) : "v"(lo), "v"(hi));
  return r;
}

#define GLOAD_LDS16(g, l) \
  __builtin_amdgcn_global_load_lds((const __attribute__((address_space(1))) void*)(g), \
                                   (__attribute__((address_space(3))) void*)(l), 16, 0, 0)

// ---------------- merged prep: cast x -> bf16 | transpose w_attn | w_proj ---
__global__ __launch_bounds__(256)
void prep_k(const float* __restrict__ x, short* __restrict__ xb,
            const float* __restrict__ wa, short* __restrict__ wat,
            const float* __restrict__ wp, short* __restrict__ wpt) {
  __shared__ float tl[32][33];
  const int bid = blockIdx.x;
  if (bid < 4096) {
    const size_t i = ((size_t)bid * 256 + threadIdx.x) * 4;
    const float4 v = *(const float4*)(x + i);
    uint2 o; o.x = pk2(v.x, v.y); o.y = pk2(v.z, v.w);
    *(uint2*)(xb + i) = o;
    return;
  }
  const float* w; short* wt; int N, t;
  if (bid < 4096 + 3072) { w = wa; wt = wat; N = 3 * DM; t = bid - 4096; }
  else { w = wp; wt = wpt; N = DM; t = bid - 7168; }
  const int nb = (N == DM) ? 32 : 96;
  const int n0 = (t % nb) * 32, k0 = (t / nb) * 32;
  const int tx = threadIdx.x & 31, ty = threadIdx.x >> 5;   // 32 x 8
  #pragma unroll
  for (int i = 0; i < 4; ++i) {
    const int kk = ty + i * 8;
    tl[kk][tx] = w[(size_t)(k0 + kk) * N + n0 + tx];
  }
  __syncthreads();
  #pragma unroll
  for (int i = 0; i < 4; ++i) {
    const int nn = ty + i * 8;
    wt[(size_t)(n0 + nn) * 1024 + k0 + tx] = f2s(tl[tx][nn]);
  }
}

// ---------------- prep: transpose present-v fp32 [bh][s][64] -> bf16 [bh][64][s]
// Keys written in PI-permuted order within each 64-key chunk:
//   PI(pos) = (pos&32) | ((pos&31)>>1) | ((pos&1)<<4)
// PV in attn contracts by POSITION, so permuting both P and V^T is exact.
__global__ __launch_bounds__(256)
void v_tr_k(const float* __restrict__ vf, short* __restrict__ vt) {
  __shared__ float tl[64][65];
  const int bh = blockIdx.x;                 // 0..31
  const int s0 = blockIdx.y * 64;            // 32 tiles (64-key chunks)
  const int tr = threadIdx.x >> 2;           // 0..63
  const int tc = (threadIdx.x & 3) * 16;
  const float* src = vf + ((size_t)bh * SS + s0) * KD;
  #pragma unroll
  for (int i = 0; i < 4; ++i) {
    const float4 v = *(const float4*)(src + (size_t)tr * KD + tc + i * 4);
    tl[tr][tc + i * 4 + 0] = v.x; tl[tr][tc + i * 4 + 1] = v.y;
    tl[tr][tc + i * 4 + 2] = v.z; tl[tr][tc + i * 4 + 3] = v.w;
  }
  __syncthreads();
  uint4 o0, o1;
  unsigned int* p0 = (unsigned int*)&o0;
  unsigned int* p1 = (unsigned int*)&o1;
  #pragma unroll
  for (int j = 0; j < 4; ++j) {
    int pos = tc + 2 * j;
    int k0 = (pos & 32) | ((pos & 31) >> 1) | ((pos & 1) << 4);
    int k1 = ((pos + 1) & 32) | (((pos + 1) & 31) >> 1) | (((pos + 1) & 1) << 4);
    p0[j] = pk2(tl[k0][tr], tl[k1][tr]);
  }
  #pragma unroll
  for (int j = 0; j < 4; ++j) {
    int pos = tc + 8 + 2 * j;
    int k0 = (pos & 32) | ((pos & 31) >> 1) | ((pos & 1) << 4);
    int k1 = ((pos + 1) & 32) | (((pos + 1) & 31) >> 1) | (((pos + 1) & 1) << 4);
    p1[j] = pk2(tl[k0][tr], tl[k1][tr]);
  }
  short* dst = vt + ((size_t)bh * KD + tr) * SS + s0 + tc;
  *(uint4*)(dst) = o0;
  *(uint4*)(dst + 8) = o1;
}

// ---------------- double-buffered MFMA GEMM core (attn-proven 2-phase) ------
// Same BK=32 m97 fragment paths, but stage(k+1) issued into the alternate
// LDS buffer BEFORE computing k, single barrier per iter — the barrier's
// vmcnt drain waits on loads that had a full compute phase to land (the fix
// that took attn 87->77 in R6). LDS 2x16 KB.
__device__ __forceinline__ void stage_ab(const short* __restrict__ A,
                                         const short* __restrict__ Bt,
                                         int m0, int n0, int k0,
                                         short* Asb, short* Bsb, int tid) {
  #pragma unroll
  for (int j = 0; j < 2; ++j) {
    const int e = j * 256 + tid;          // 0..511
    const int r = e >> 2, cq = e & 3;     // row, 16B-chunk
    GLOAD_LDS16(A  + (size_t)(m0 + r) * 1024 + k0 + cq * 8, Asb + e * 8);
    GLOAD_LDS16(Bt + (size_t)(n0 + r) * 1024 + k0 + cq * 8, Bsb + e * 8);
  }
}
__device__ __forceinline__ void mfma_tile_loop(
    const short* __restrict__ A, const short* __restrict__ Bt,
    int m0, int n0, short* Asm, short* Bsm, f32x4 (*acc)[4]) {
  // Asm/Bsm are [2][128*32]
  const int tid = threadIdx.x;
  const int lane = tid & 63;
  const int w = tid >> 6;
  const int wm = (w >> 1) * 64, wn = (w & 1) * 64;
  const int ln15 = lane & 15, quad = lane >> 4;
  stage_ab(A, Bt, m0, n0, 0, Asm, Bsm, tid);
  __syncthreads();
  for (int k0 = 0; k0 < 1024; k0 += 32) {
    const int cur = (k0 >> 5) & 1;
    if (k0 + 32 < 1024)
      stage_ab(A, Bt, m0, n0, k0 + 32,
               Asm + (cur ^ 1) * (128 * 32), Bsm + (cur ^ 1) * (128 * 32), tid);
    const short* Ac = Asm + cur * (128 * 32);
    const short* Bc = Bsm + cur * (128 * 32);
    short8 af[4], bf[4];
    #pragma unroll
    for (int t = 0; t < 4; ++t)
      af[t] = *(const short8*)(Ac + (wm + t * 16 + ln15) * 32 + quad * 8);
    #pragma unroll
    for (int t = 0; t < 4; ++t)
      bf[t] = *(const short8*)(Bc + (wn + t * 16 + ln15) * 32 + quad * 8);
    #pragma unroll
    for (int tm = 0; tm < 4; ++tm)
      #pragma unroll
      for (int tn = 0; tn < 4; ++tn)
        acc[tm][tn] = __builtin_amdgcn_mfma_f32_16x16x32_bf16(
            af[tm], bf[tn], acc[tm][tn], 0, 0, 0);
    __syncthreads();   // next buf staged+visible; cur reads done before overwrite
  }
}

// ---------------- QKV GEMM: routes v,q,k = split(qkv) ----------------------
// Grid 768 linear; 2D XCD partition: XCD (xcd>>1, xcd&1) owns m-panels
// [8*(xcd>>1), +8) x n-panels [12*(xcd&1), +12) — per-XCD working set
// ~2MB A + 3MB B fits the 4MB L2 (vs full replication before; FETCH 40MB).
__global__ __launch_bounds__(256)
void qkv_mfma_k(const short* __restrict__ A, const short* __restrict__ Bt,
                const float* __restrict__ bias, short* __restrict__ qbf,
                float* __restrict__ outf, short* __restrict__ kbf) {
  __shared__ short Asm[2][128 * 32];
  __shared__ short Bsm[2][128 * 32];
  const int bid = blockIdx.x;
  const int xcd = bid & 7, g = bid >> 3;          // g 0..95
  const int mp = ((xcd >> 1) << 3) | (g & 7);     // m-panel 0..31
  const int np = (xcd & 1) * 12 + (g >> 3);       // n-panel 0..23
  const int n0 = np * 128, m0 = mp * 128;
  f32x4 acc[4][4] = {};
  mfma_tile_loop(A, Bt, m0, n0, &Asm[0][0], &Bsm[0][0], acc);
  const int lane = threadIdx.x & 63;
  const int w = threadIdx.x >> 6;
  const int wm = (w >> 1) * 64, wn = (w & 1) * 64;
  const int col = lane & 15, row4 = (lane >> 4) * 4;
  const int mbase = m0 + wm;
  const int bb = mbase >> 11;                    // block-uniform
  const int sbase = (mbase & 2047) + row4;
  #pragma unroll
  for (int tn = 0; tn < 4; ++tn) {
    const int n = n0 + wn + tn * 16 + col;
    const float bv = bias[n];
    const int c = n & 1023, h = c >> 6, d = c & 63;
    const size_t base = ((size_t)(bb * NH + h) * SS) * KD + d;
    #pragma unroll
    for (int tm = 0; tm < 4; ++tm) {
      const size_t sb = base + (size_t)(sbase + tm * 16) * KD;
      #pragma unroll
      for (int r = 0; r < 4; ++r) {
        const float val = acc[tm][tn][r] + bv;
        const size_t idx = sb + (size_t)r * KD;
        if (n < DM) {
          outf[(size_t)OUT_ELEMS + (size_t)PRES_HALF + idx] = val;   // v fp32
        } else if (n < 2 * DM) {
          qbf[idx] = f2s_hw(val);                                     // q bf16
        } else {
          outf[(size_t)OUT_ELEMS + idx] = val;                        // k fp32
          if (kbf) kbf[idx] = f2s_hw(val);
        }
      }
    }
  }
}

// ---------------- Output projection: o @ w_projT + b -> out0 fp32 -----------
// 128x64 tiles, 512 blocks = 2/CU; double-buffered staging; XCD partition:
// XCD owns m-panels [4*xcd, +4) x all 16 n-panels (~1MB A + 2MB B, L2-fit).
__global__ __launch_bounds__(256)
void proj_mfma_k(const short* __restrict__ A, const short* __restrict__ Bt,
                 const float* __restrict__ bias, float* __restrict__ outf) {
  __shared__ short Asm[2][128 * 32];
  __shared__ short Bsm[2][64 * 32];
  const int bid = blockIdx.x;
  const int xcd = bid & 7, g = bid >> 3;          // g 0..63
  const int m0 = ((xcd << 2) | (g & 3)) * 128;    // m-panel 0..31
  const int n0 = (g >> 2) * 64;                   // n-panel 0..15
  const int tid = threadIdx.x;
  const int lane = tid & 63;
  const int w = tid >> 6;
  const int wm = (w >> 1) * 64, wn = (w & 1) * 32;
  const int ln15 = lane & 15, quad = lane >> 4;
  f32x4 acc[4][2] = {};
  // prologue stage k0=0 -> buf 0
  {
    #pragma unroll
    for (int j = 0; j < 2; ++j) {
      const int e = j * 256 + tid;
      const int r = e >> 2, cq = e & 3;
      GLOAD_LDS16(A + (size_t)(m0 + r) * 1024 + cq * 8, &Asm[0][0] + e * 8);
    }
    const int r = tid >> 2, cq = tid & 3;
    GLOAD_LDS16(Bt + (size_t)(n0 + r) * 1024 + cq * 8, &Bsm[0][0] + tid * 8);
  }
  __syncthreads();
  for (int k0 = 0; k0 < 1024; k0 += 32) {
    const int cur = (k0 >> 5) & 1;
    if (k0 + 32 < 1024) {
      short* Asb = &Asm[cur ^ 1][0];
      short* Bsb = &Bsm[cur ^ 1][0];
      #pragma unroll
      for (int j = 0; j < 2; ++j) {
        const int e = j * 256 + tid;
        const int r = e >> 2, cq = e & 3;
        GLOAD_LDS16(A + (size_t)(m0 + r) * 1024 + k0 + 32 + cq * 8, Asb + e * 8);
      }
      const int r = tid >> 2, cq = tid & 3;
      GLOAD_LDS16(Bt + (size_t)(n0 + r) * 1024 + k0 + 32 + cq * 8, Bsb + tid * 8);
    }
    const short* Ac = &Asm[cur][0];
    const short* Bc = &Bsm[cur][0];
    short8 af[4], bf[2];
    #pragma unroll
    for (int t = 0; t < 4; ++t)
      af[t] = *(const short8*)(Ac + (wm + t * 16 + ln15) * 32 + quad * 8);
    #pragma unroll
    for (int t = 0; t < 2; ++t)
      bf[t] = *(const short8*)(Bc + (wn + t * 16 + ln15) * 32 + quad * 8);
    #pragma unroll
    for (int tm = 0; tm < 4; ++tm)
      #pragma unroll
      for (int tn = 0; tn < 2; ++tn)
        acc[tm][tn] = __builtin_amdgcn_mfma_f32_16x16x32_bf16(
            af[tm], bf[tn], acc[tm][tn], 0, 0, 0);
    __syncthreads();
  }
  const int col = ln15, row4 = quad * 4;
  #pragma unroll
  for (int tm = 0; tm < 4; ++tm) {
    #pragma unroll
    for (int tn = 0; tn < 2; ++tn) {
      const int n = n0 + wn + tn * 16 + col;
      const float b = bias[n];
      #pragma unroll
      for (int r = 0; r < 4; ++r) {
        const int m = m0 + wm + tm * 16 + row4 + r;
        outf[(size_t)m * DM + n] = acc[tm][tn][r] + b;
      }
    }
  }
}

// ---------------- staging: one 64-key chunk of K + V^T, 256 threads ---------
__device__ __forceinline__ void stage_kv4(const short* __restrict__ Kg,
                                          const short* __restrict__ Vg,
                                          int kb, short* Ksb, short* Vtb,
                                          int tid) {
  #pragma unroll
  for (int rd = 0; rd < 2; ++rd) {
    const int i = rd * 256 + tid;        // 0..511 : row = i>>3, grp = i&7
    const int row = i >> 3, grp = i & 7;
    const int sw = (grp ^ (row & 7)) << 3;
    GLOAD_LDS16(Kg + (size_t)(kb + row) * KD + sw, Ksb + i * 8);
    GLOAD_LDS16(Vg + (size_t)row * SS + kb + sw, Vtb + i * 8);
  }
}

// ---------------- MFMA causal flash attention (R11 — frozen best) -----------
__global__ __launch_bounds__(256)
void attn_mfma9_k(const short* __restrict__ qbf, const short* __restrict__ kbf,
                  const short* __restrict__ vbft, short* __restrict__ obf) {
  __shared__ short Ks[2][64 * 64];    // K chunk  [key][d], swizzled
  __shared__ short Vt[2][64 * 64];    // V^T chunk [d][pos], swizzled (PI order)
  __shared__ short Ps[4][16 * 64];    // per-wave P [qrow][pos], swizzled
  const int bid = blockIdx.x;                     // 0..511
  const int xcd = bid & 7, g = bid >> 3;          // g 0..63
  const int rnd = g >> 4;                         // head-in-XCD 0..3
  const int p   = g & 15;                         // causal pair 0..15
  const int bh  = (xcd << 2) | rnd;
  const int tid = threadIdx.x;
  const int w   = tid >> 6;
  const int lane = tid & 63;
  const int ln15 = lane & 15, quad = lane >> 4;
  const int rswz = (ln15 & 7) << 3;               // fragment-read swizzle
  const float SC2 = 0.125f * 1.44269504f;         // scale * log2(e)
  const float THR = 8.0f;                         // defer-max threshold (raw)

  const short* Kg = kbf  + (size_t)bh * SS * KD;
  const short* Vg = vbft + (size_t)bh * KD * SS;
  short* Pw = Ps[w];
  const int bb = bh >> 4, h = bh & 15;

  #pragma unroll 1
  for (int pass = 0; pass < 2; ++pass) {
    const int qb = pass ? (31 - p) : p;
    const int q0 = qb * 64;
    const int nch = qb + 1;

    short8 aq[2];
    {
      const short* qp = qbf + ((size_t)bh * SS + q0 + w * 16) * KD;
      aq[0] = *(const short8*)(qp + (size_t)ln15 * KD + quad * 8);
      aq[1] = *(const short8*)(qp + (size_t)ln15 * KD + 32 + quad * 8);
    }
    f32x4 O[4] = {};                    // [tn], rows quad*4+r
    float mreg[4], lreg[4];             // [r]
    #pragma unroll
    for (int r = 0; r < 4; ++r) { mreg[r] = NEGSENT; lreg[r] = 0.f; }

    stage_kv4(Kg, Vg, 0, Ks[0], Vt[0], tid);   // chunk 0 -> buf 0
    __syncthreads();

    for (int ch = 0; ch < nch; ++ch) {
      const int cur = ch & 1;
      if (ch + 1 < nch)                        // issue next-chunk loads first
        stage_kv4(Kg, Vg, (ch + 1) * 64, Ks[cur ^ 1], Vt[cur ^ 1], tid);
      const short* Kc = Ks[cur];
      const short* Vc = Vt[cur];

      // ---- QK^T: S[16 q][64 k] (actual key order) ----
      f32x4 S[4] = {};
      #pragma unroll
      for (int kt = 0; kt < 2; ++kt) {
        short8 bk[4];
        #pragma unroll
        for (int tn = 0; tn < 4; ++tn)
          bk[tn] = *(const short8*)(Kc + (tn * 16 + ln15) * 64 + ((kt * 32 + quad * 8) ^ rswz));
        #pragma unroll
        for (int tn = 0; tn < 4; ++tn)
          S[tn] = __builtin_amdgcn_mfma_f32_16x16x32_bf16(aq[kt], bk[tn], S[tn], 0, 0, 0);
      }

      // ---- causal mask on the diagonal chunk ----
      if (ch == qb) {
        const int rowl = w * 16 + quad * 4;
        #pragma unroll
        for (int tn = 0; tn < 4; ++tn) {
          const int colk = tn * 16 + ln15;
          #pragma unroll
          for (int r = 0; r < 4; ++r)
            if (colk > rowl + r) S[tn][r] = NEGSENT;
        }
      }

      // ---- cheap per-lane defer-max check (conservative, no shfl) ----
      {
        float lmax = S[0][0];
        #pragma unroll
        for (int tn = 0; tn < 4; ++tn)
          #pragma unroll
          for (int r = 0; r < 4; ++r) lmax = fmaxf(lmax, S[tn][r]);
        const float mmin = fminf(fminf(mreg[0], mreg[1]), fminf(mreg[2], mreg[3]));
        const bool ok = (lmax - mmin) <= THR;
        if (!__all((int)ok)) {                  // rare slow path: full rescale
          #pragma unroll
          for (int r = 0; r < 4; ++r) {
            float mx = fmaxf(fmaxf(fmaxf(S[0][r], S[1][r]), S[2][r]), S[3][r]);
            mx = fmaxf(mx, __shfl_xor(mx, 1, 64));
            mx = fmaxf(mx, __shfl_xor(mx, 2, 64));
            mx = fmaxf(mx, __shfl_xor(mx, 4, 64));
            mx = fmaxf(mx, __shfl_xor(mx, 8, 64));
            const float mn = fmaxf(mreg[r], mx);
            const float al = exp2f((mreg[r] - mn) * SC2);
            mreg[r] = mn;
            lreg[r] *= al;
            O[0][r] *= al; O[1][r] *= al; O[2][r] *= al; O[3][r] *= al;
          }
        }
      }

      // ---- P = exp2(fma(S,SC2,-m*SC2)); l += ...; packed P stores ----
      #pragma unroll
      for (int r = 0; r < 4; ++r) {
        const float mnsc = mreg[r] * SC2;
        const int prow = quad * 4 + r;
        const int rs = (prow & 7) << 3;
        float p0 = exp2f(fmaf(S[0][r], SC2, -mnsc));
        float p1 = exp2f(fmaf(S[1][r], SC2, -mnsc));
        float p2 = exp2f(fmaf(S[2][r], SC2, -mnsc));
        float p3 = exp2f(fmaf(S[3][r], SC2, -mnsc));
        lreg[r] += (p0 + p1) + (p2 + p3);
        *(unsigned int*)(Pw + prow * 64 + ((2 * ln15) ^ rs))      = pk2(p0, p1);
        *(unsigned int*)(Pw + prow * 64 + ((32 + 2 * ln15) ^ rs)) = pk2(p2, p3);
      }
      asm volatile("s_waitcnt lgkmcnt(0)" ::: "memory");  // own P writes landed
      __builtin_amdgcn_sched_barrier(0);                  // rule 18

      // ---- PV: O += P @ V (contraction by position; both PI-ordered) ----
      #pragma unroll
      for (int kt = 0; kt < 2; ++kt) {
        short8 ap = *(const short8*)(Pw + ln15 * 64 + ((kt * 32 + quad * 8) ^ rswz));
        short8 bv[4];
        #pragma unroll
        for (int tn = 0; tn < 4; ++tn)
          bv[tn] = *(const short8*)(Vc + (tn * 16 + ln15) * 64 + ((kt * 32 + quad * 8) ^ rswz));
        #pragma unroll
        for (int tn = 0; tn < 4; ++tn)
          O[tn] = __builtin_amdgcn_mfma_f32_16x16x32_bf16(ap, bv[tn], O[tn], 0, 0, 0);
      }
      __syncthreads();   // next buf staged+visible; prev reads done
    }

    // ---- finalize l and write o token-major (no LDS access) ----
    #pragma unroll
    for (int r = 0; r < 4; ++r) {
      float l = lreg[r];
      l += __shfl_xor(l, 1, 64);
      l += __shfl_xor(l, 2, 64);
      l += __shfl_xor(l, 4, 64);
      l += __shfl_xor(l, 8, 64);
      lreg[r] = 1.f / fmaxf(l, 1e-30f);
    }
    short* ob = obf + ((size_t)bb * SS + q0 + w * 16) * DM + h * KD;
    #pragma unroll
    for (int tn = 0; tn < 4; ++tn)
      #pragma unroll
      for (int r = 0; r < 4; ++r)
        ob[(size_t)(quad * 4 + r) * DM + tn * 16 + ln15] = f2s_hw(O[tn][r] * lreg[r]);
  }
}

// ---------------- legacy fp32 flash attention (fallback, small ws) ----------
__global__ __launch_bounds__(256)
void attn_k(const short* __restrict__ qbf, const float* __restrict__ pres,
            short* __restrict__ obf) {
  __shared__ float Ksf[32][64];
  __shared__ float Vsf[32][64];
  const int bh = blockIdx.x;
  const int q0 = ((int)gridDim.y - 1 - (int)blockIdx.y) * 64;
  const int t  = threadIdx.x;
  const int part = t & 3;
  const int row  = t >> 2;
  const int qr   = q0 + row;
  const int dbase = part * 16;
  const size_t qoff = ((size_t)bh * SS + qr) * KD + dbase;
  float q[16], o[16];
  #pragma unroll
  for (int i = 0; i < 16; ++i) q[i] = us2f((unsigned short)qbf[qoff + i]);
  #pragma unroll
  for (int i = 0; i < 16; ++i) o[i] = 0.f;
  float m = NEGSENT, l = 0.f;
  const float* Kb = pres + (size_t)bh * SS * KD;
  const float* Vb = pres + (size_t)PRES_HALF + (size_t)bh * SS * KD;
  const int nch = (q0 + 64) / 32;
  for (int ch = 0; ch < nch; ++ch) {
    const int kbase = ch * 32;
    __syncthreads();
    {
      const float4* ksrc = (const float4*)(Kb + (size_t)kbase * KD);
      const float4* vsrc = (const float4*)(Vb + (size_t)kbase * KD);
      float4* kdst = (float4*)&Ksf[0][0];
      float4* vdst = (float4*)&Vsf[0][0];
      #pragma unroll
      for (int i = 0; i < 2; ++i) {
        kdst[t + i * 256] = ksrc[t + i * 256];
        vdst[t + i * 256] = vsrc[t + i * 256];
      }
    }
    __syncthreads();
    float sc[32];
    #pragma unroll
    for (int kk = 0; kk < 32; ++kk) {
      float s = 0.f;
      #pragma unroll
      for (int i = 0; i < 16; ++i) s = fmaf(q[i], Ksf[kk][dbase + i], s);
      s += __shfl_xor(s, 1, 64);
      s += __shfl_xor(s, 2, 64);
      sc[kk] = (kbase + kk <= qr) ? s * 0.125f : NEGSENT;
    }
    float mc = sc[0];
    #pragma unroll
    for (int kk = 1; kk < 32; ++kk) mc = fmaxf(mc, sc[kk]);
    const float mn = fmaxf(m, mc);
    const float alpha = __expf(m - mn);
    l *= alpha;
    #pragma unroll
    for (int i = 0; i < 16; ++i) o[i] *= alpha;
    #pragma unroll
    for (int kk = 0; kk < 32; ++kk) {
      const float p = __expf(sc[kk] - mn);
      l += p;
      #pragma unroll
      for (int i = 0; i < 16; ++i) o[i] = fmaf(p, Vsf[kk][dbase + i], o[i]);
    }
    m = mn;
  }
  const float inv = 1.f / fmaxf(l, 1e-30f);
  const int bb = bh >> 4, h = bh & 15;
  const size_t ooff = ((size_t)(bb * SS + qr)) * DM + h * KD + dbase;
  #pragma unroll
  for (int i = 0; i < 16; ++i) obf[ooff + i] = f2s(o[i] * inv);
}

extern "C" void kernel_launch(void* const* d_in, const int* in_sizes, int n_in,
                              void* d_out, int out_size, void* d_ws, size_t ws_size,
                              hipStream_t stream) {
  const float* x      = (const float*)d_in[0];
  const float* w_attn = (const float*)d_in[2];
  const float* b_attn = (const float*)d_in[3];
  const float* w_proj = (const float*)d_in[4];
  const float* b_proj = (const float*)d_in[5];
  float* outf = (float*)d_out;   // fp32: [out0 4M | k 4M | v 4M] elements

  constexpr size_t MB = 1024 * 1024;
  if (ws_size >= 24 * MB) {
    // ---- MFMA-attention path ----
    short* ws0   = (short*)d_ws;
    short* x_bf  = ws0;
    short* o_bf  = ws0;
    short* wat_t = ws0 + (size_t)4 * 1024 * 1024;
    short* wpt_t = ws0 + (size_t)7 * 1024 * 1024;
    short* q_bf  = ws0 + (size_t)8 * 1024 * 1024;
    short* k_bf  = (short*)d_out;
    short* v_bft = k_bf + (size_t)PRES_HALF;

    prep_k<<<8192, 256, 0, stream>>>(x, x_bf, w_attn, wat_t, w_proj, wpt_t);

    qkv_mfma_k<<<768, 256, 0, stream>>>(x_bf, wat_t, b_attn, q_bf, outf, k_bf);

    v_tr_k<<<dim3(BB * NH, SS / 64), 256, 0, stream>>>(
        outf + OUT_ELEMS + PRES_HALF, v_bft);

    attn_mfma9_k<<<dim3(512), 256, 0, stream>>>(q_bf, k_bf, v_bft, o_bf);

    proj_mfma_k<<<512, 256, 0, stream>>>(o_bf, wpt_t, b_proj, outf);
  } else {
    // ---- legacy fp32-attention fallback ----
    short* x_bf;
    short* q_bf;
    short* wat_t;
    short* wpt_t;
    short* o_bf;
    if (ws_size >= 16 * MB) {
      short* ws = (short*)d_ws;
      x_bf  = (short*)d_out;                 // out0 [0,8MB) dead until proj
      q_bf  = x_bf + OUT_ELEMS;              // out0 [8MB,16MB)
      wat_t = ws;
      wpt_t = wat_t + 3 * DM * DM;
      o_bf  = wat_t + 4 * DM * DM;
    } else {
      x_bf  = (short*)d_out;
      q_bf  = x_bf + OUT_ELEMS;
      wat_t = (short*)d_in[1];
      wpt_t = wat_t + 3 * DM * DM;
      o_bf  = wat_t + 4 * DM * DM;
    }
    prep_k<<<8192, 256, 0, stream>>>(x, x_bf, w_attn, wat_t, w_proj, wpt_t);
    qkv_mfma_k<<<768, 256, 0, stream>>>(x_bf, wat_t, b_attn, q_bf, outf, nullptr);
    attn_k<<<dim3(BB * NH, SS / 64), 256, 0, stream>>>(q_bf, outf + OUT_ELEMS, o_bf);
    proj_mfma_k<<<512, 256, 0, stream>>>(o_bf, wpt_t, b_proj, outf);
  }
}

// Round 15
// 218.861 us; speedup vs baseline: 1.0305x; 1.0305x over previous
//
#include <hip/hip_runtime.h>
#include <math.h>

constexpr int BB = 2;
constexpr int SS = 2048;
constexpr int DM = 1024;
constexpr int NH = 16;
constexpr int KD = 64;
constexpr int OUT_ELEMS  = BB*SS*DM;     // 4194304 fp32 (output 0 region)
constexpr int PRES_HALF  = BB*NH*SS*KD;  // 4194304 fp32 (k or v)
#define NEGSENT (-1e30f)

typedef __attribute__((ext_vector_type(8))) short short8;   // 8 x bf16 bits
typedef __attribute__((ext_vector_type(4))) short short4v;  // 4 x bf16 bits
typedef __attribute__((ext_vector_type(4))) float f32x4;

__device__ __forceinline__ float us2f(unsigned short u) {
  union { unsigned int ui; float f; } c; c.ui = ((unsigned int)u) << 16; return c.f;
}
__device__ __forceinline__ short f2s(float f) {
  // round-to-nearest-even bf16 (finite inputs only) — software path
  union { float f; unsigned int u; } c; c.f = f;
  return (short)((c.u + 0x7FFFu + ((c.u >> 16) & 1u)) >> 16);
}
__device__ __forceinline__ short f2s_hw(float f) {
  // hardware RNE bf16 via v_cvt_pk_bf16_f32 (no builtin on gfx950 — T12).
  unsigned int r;
  asm("v_cvt_pk_bf16_f32 %0, %1, %1" : "=v"(r) : "v"(f));
  return (short)r;
}
__device__ __forceinline__ unsigned int pk2(float lo, float hi) {
  // [bf16(lo) | bf16(hi)<<16] in one instruction (S0->low, S1->high)
  unsigned int r;
  asm("v_cvt_pk_bf16_f32 %0, %1, %2" : "=v"(r) : "v"(lo), "v"(hi));
  return r;
}

#define GLOAD_LDS16(g, l) \
  __builtin_amdgcn_global_load_lds((const __attribute__((address_space(1))) void*)(g), \
                                   (__attribute__((address_space(3))) void*)(l), 16, 0, 0)

// ---------------- merged prep: cast x -> bf16 | transpose w_attn | w_proj ---
__global__ __launch_bounds__(256)
void prep_k(const float* __restrict__ x, short* __restrict__ xb,
            const float* __restrict__ wa, short* __restrict__ wat,
            const float* __restrict__ wp, short* __restrict__ wpt) {
  __shared__ float tl[32][33];
  const int bid = blockIdx.x;
  if (bid < 4096) {
    const size_t i = ((size_t)bid * 256 + threadIdx.x) * 4;
    const float4 v = *(const float4*)(x + i);
    uint2 o; o.x = pk2(v.x, v.y); o.y = pk2(v.z, v.w);
    *(uint2*)(xb + i) = o;
    return;
  }
  const float* w; short* wt; int N, t;
  if (bid < 4096 + 3072) { w = wa; wt = wat; N = 3 * DM; t = bid - 4096; }
  else { w = wp; wt = wpt; N = DM; t = bid - 7168; }
  const int nb = (N == DM) ? 32 : 96;
  const int n0 = (t % nb) * 32, k0 = (t / nb) * 32;
  const int tx = threadIdx.x & 31, ty = threadIdx.x >> 5;   // 32 x 8
  #pragma unroll
  for (int i = 0; i < 4; ++i) {
    const int kk = ty + i * 8;
    tl[kk][tx] = w[(size_t)(k0 + kk) * N + n0 + tx];
  }
  __syncthreads();
  #pragma unroll
  for (int i = 0; i < 4; ++i) {
    const int nn = ty + i * 8;
    wt[(size_t)(n0 + nn) * 1024 + k0 + tx] = f2s_hw(tl[tx][nn]);
  }
}

// ---------------- prep: transpose present-v fp32 [bh][s][64] -> bf16 [bh][64][s]
// Keys written in PI-permuted order within each 64-key chunk:
//   PI(pos) = (pos&32) | ((pos&31)>>1) | ((pos&1)<<4)
// PV in attn contracts by POSITION, so permuting both P and V^T is exact.
__global__ __launch_bounds__(256)
void v_tr_k(const float* __restrict__ vf, short* __restrict__ vt) {
  __shared__ float tl[64][65];
  const int bh = blockIdx.x;                 // 0..31
  const int s0 = blockIdx.y * 64;            // 32 tiles (64-key chunks)
  const int tr = threadIdx.x >> 2;           // 0..63
  const int tc = (threadIdx.x & 3) * 16;
  const float* src = vf + ((size_t)bh * SS + s0) * KD;
  #pragma unroll
  for (int i = 0; i < 4; ++i) {
    const float4 v = *(const float4*)(src + (size_t)tr * KD + tc + i * 4);
    tl[tr][tc + i * 4 + 0] = v.x; tl[tr][tc + i * 4 + 1] = v.y;
    tl[tr][tc + i * 4 + 2] = v.z; tl[tr][tc + i * 4 + 3] = v.w;
  }
  __syncthreads();
  uint4 o0, o1;
  unsigned int* p0 = (unsigned int*)&o0;
  unsigned int* p1 = (unsigned int*)&o1;
  #pragma unroll
  for (int j = 0; j < 4; ++j) {
    int pos = tc + 2 * j;
    int k0 = (pos & 32) | ((pos & 31) >> 1) | ((pos & 1) << 4);
    int k1 = ((pos + 1) & 32) | (((pos + 1) & 31) >> 1) | (((pos + 1) & 1) << 4);
    p0[j] = pk2(tl[k0][tr], tl[k1][tr]);
  }
  #pragma unroll
  for (int j = 0; j < 4; ++j) {
    int pos = tc + 8 + 2 * j;
    int k0 = (pos & 32) | ((pos & 31) >> 1) | ((pos & 1) << 4);
    int k1 = ((pos + 1) & 32) | (((pos + 1) & 31) >> 1) | (((pos + 1) & 1) << 4);
    p1[j] = pk2(tl[k0][tr], tl[k1][tr]);
  }
  short* dst = vt + ((size_t)bh * KD + tr) * SS + s0 + tc;
  *(uint4*)(dst) = o0;
  *(uint4*)(dst + 8) = o1;
}

// ---------------- MFMA GEMM core (m97 structure, BK=32 — proven best) -------
// R15: reverted to the plain 2-barrier loop. Both structural variants lost:
// BK=64 (R7, bank conflicts / occupancy), explicit dbuf + XCD partition
// (R13/R14, 219.3 -> 225.5). Matches learn_hip m99/m100: explicit dbuf on
// the m97 structure is neutral-to-negative; cross-block overlap already
// hides the barrier drain at 3 blocks/CU.
__device__ __forceinline__ void mfma_tile_loop(
    const short* __restrict__ A, const short* __restrict__ Bt,
    int m0, int n0, short* Asm, short* Bsm, f32x4 (*acc)[4]) {
  const int tid = threadIdx.x;
  const int lane = tid & 63;
  const int w = tid >> 6;
  const int wm = (w >> 1) * 64, wn = (w & 1) * 64;
  const int ln15 = lane & 15, quad = lane >> 4;
  for (int k0 = 0; k0 < 1024; k0 += 32) {
    #pragma unroll
    for (int j = 0; j < 2; ++j) {
      const int e = j * 256 + tid;          // 0..511
      const int r = e >> 2, cq = e & 3;     // row, 16B-chunk
      GLOAD_LDS16(A  + (size_t)(m0 + r) * 1024 + k0 + cq * 8, Asm + e * 8);
      GLOAD_LDS16(Bt + (size_t)(n0 + r) * 1024 + k0 + cq * 8, Bsm + e * 8);
    }
    __syncthreads();                        // drains vmcnt before barrier
    short8 af[4], bf[4];
    #pragma unroll
    for (int t = 0; t < 4; ++t)
      af[t] = *(const short8*)(Asm + (wm + t * 16 + ln15) * 32 + quad * 8);
    #pragma unroll
    for (int t = 0; t < 4; ++t)
      bf[t] = *(const short8*)(Bsm + (wn + t * 16 + ln15) * 32 + quad * 8);
    #pragma unroll
    for (int tm = 0; tm < 4; ++tm)
      #pragma unroll
      for (int tn = 0; tn < 4; ++tn)
        acc[tm][tn] = __builtin_amdgcn_mfma_f32_16x16x32_bf16(
            af[tm], bf[tn], acc[tm][tn], 0, 0, 0);
    __syncthreads();
  }
}

// ---------------- QKV GEMM: routes v,q,k = split(qkv) ----------------------
// Epilogue strength-reduced (R12): bb block-uniform, h/d/branch per-tn
// uniform, idx affine in (tm,r).
__global__ __launch_bounds__(256)
void qkv_mfma_k(const short* __restrict__ A, const short* __restrict__ Bt,
                const float* __restrict__ bias, short* __restrict__ qbf,
                float* __restrict__ outf, short* __restrict__ kbf) {
  __shared__ short Asm[128 * 32];
  __shared__ short Bsm[128 * 32];
  const int n0 = blockIdx.x * 128, m0 = blockIdx.y * 128;
  f32x4 acc[4][4] = {};
  mfma_tile_loop(A, Bt, m0, n0, Asm, Bsm, acc);
  const int lane = threadIdx.x & 63;
  const int w = threadIdx.x >> 6;
  const int wm = (w >> 1) * 64, wn = (w & 1) * 64;
  const int col = lane & 15, row4 = (lane >> 4) * 4;
  const int mbase = m0 + wm;
  const int bb = mbase >> 11;                    // block-uniform
  const int sbase = (mbase & 2047) + row4;
  #pragma unroll
  for (int tn = 0; tn < 4; ++tn) {
    const int n = n0 + wn + tn * 16 + col;
    const float bv = bias[n];
    const int c = n & 1023, h = c >> 6, d = c & 63;
    const size_t base = ((size_t)(bb * NH + h) * SS) * KD + d;
    #pragma unroll
    for (int tm = 0; tm < 4; ++tm) {
      const size_t sb = base + (size_t)(sbase + tm * 16) * KD;
      #pragma unroll
      for (int r = 0; r < 4; ++r) {
        const float val = acc[tm][tn][r] + bv;
        const size_t idx = sb + (size_t)r * KD;
        if (n < DM) {
          outf[(size_t)OUT_ELEMS + (size_t)PRES_HALF + idx] = val;   // v fp32
        } else if (n < 2 * DM) {
          qbf[idx] = f2s_hw(val);                                     // q bf16
        } else {
          outf[(size_t)OUT_ELEMS + idx] = val;                        // k fp32
          if (kbf) kbf[idx] = f2s_hw(val);
        }
      }
    }
  }
}

// ---------------- Output projection: o @ w_projT + b -> out0 fp32 -----------
// 128x64 tiles, grid (16,32) = 512 blocks = 2/CU (R12-exact).
__global__ __launch_bounds__(256)
void proj_mfma_k(const short* __restrict__ A, const short* __restrict__ Bt,
                 const float* __restrict__ bias, float* __restrict__ outf) {
  __shared__ short Asm[128 * 32];
  __shared__ short Bsm[64 * 32];
  const int n0 = blockIdx.x * 64, m0 = blockIdx.y * 128;
  const int tid = threadIdx.x;
  const int lane = tid & 63;
  const int w = tid >> 6;
  const int wm = (w >> 1) * 64, wn = (w & 1) * 32;
  const int ln15 = lane & 15, quad = lane >> 4;
  f32x4 acc[4][2] = {};
  for (int k0 = 0; k0 < 1024; k0 += 32) {
    #pragma unroll
    for (int j = 0; j < 2; ++j) {
      const int e = j * 256 + tid;          // 0..511
      const int r = e >> 2, cq = e & 3;     // row 0..127
      GLOAD_LDS16(A + (size_t)(m0 + r) * 1024 + k0 + cq * 8, Asm + e * 8);
    }
    {
      const int r = tid >> 2, cq = tid & 3; // row 0..63
      GLOAD_LDS16(Bt + (size_t)(n0 + r) * 1024 + k0 + cq * 8, Bsm + tid * 8);
    }
    __syncthreads();
    short8 af[4], bf[2];
    #pragma unroll
    for (int t = 0; t < 4; ++t)
      af[t] = *(const short8*)(Asm + (wm + t * 16 + ln15) * 32 + quad * 8);
    #pragma unroll
    for (int t = 0; t < 2; ++t)
      bf[t] = *(const short8*)(Bsm + (wn + t * 16 + ln15) * 32 + quad * 8);
    #pragma unroll
    for (int tm = 0; tm < 4; ++tm)
      #pragma unroll
      for (int tn = 0; tn < 2; ++tn)
        acc[tm][tn] = __builtin_amdgcn_mfma_f32_16x16x32_bf16(
            af[tm], bf[tn], acc[tm][tn], 0, 0, 0);
    __syncthreads();
  }
  const int col = ln15, row4 = quad * 4;
  #pragma unroll
  for (int tm = 0; tm < 4; ++tm) {
    #pragma unroll
    for (int tn = 0; tn < 2; ++tn) {
      const int n = n0 + wn + tn * 16 + col;
      const float b = bias[n];
      #pragma unroll
      for (int r = 0; r < 4; ++r) {
        const int m = m0 + wm + tm * 16 + row4 + r;
        outf[(size_t)m * DM + n] = acc[tm][tn][r] + b;
      }
    }
  }
}

// ---------------- staging: one 64-key chunk of K + V^T, 256 threads ---------
__device__ __forceinline__ void stage_kv4(const short* __restrict__ Kg,
                                          const short* __restrict__ Vg,
                                          int kb, short* Ksb, short* Vtb,
                                          int tid) {
  #pragma unroll
  for (int rd = 0; rd < 2; ++rd) {
    const int i = rd * 256 + tid;        // 0..511 : row = i>>3, grp = i&7
    const int row = i >> 3, grp = i & 7;
    const int sw = (grp ^ (row & 7)) << 3;
    GLOAD_LDS16(Kg + (size_t)(kb + row) * KD + sw, Ksb + i * 8);
    GLOAD_LDS16(Vg + (size_t)row * SS + kb + sw, Vtb + i * 8);
  }
}

// ---------------- MFMA causal flash attention (frozen best since R11) -------
__global__ __launch_bounds__(256)
void attn_mfma9_k(const short* __restrict__ qbf, const short* __restrict__ kbf,
                  const short* __restrict__ vbft, short* __restrict__ obf) {
  __shared__ short Ks[2][64 * 64];    // K chunk  [key][d], swizzled
  __shared__ short Vt[2][64 * 64];    // V^T chunk [d][pos], swizzled (PI order)
  __shared__ short Ps[4][16 * 64];    // per-wave P [qrow][pos], swizzled
  const int bid = blockIdx.x;                     // 0..511
  const int xcd = bid & 7, g = bid >> 3;          // g 0..63
  const int rnd = g >> 4;                         // head-in-XCD 0..3
  const int p   = g & 15;                         // causal pair 0..15
  const int bh  = (xcd << 2) | rnd;
  const int tid = threadIdx.x;
  const int w   = tid >> 6;
  const int lane = tid & 63;
  const int ln15 = lane & 15, quad = lane >> 4;
  const int rswz = (ln15 & 7) << 3;               // fragment-read swizzle
  const float SC2 = 0.125f * 1.44269504f;         // scale * log2(e)
  const float THR = 8.0f;                         // defer-max threshold (raw)

  const short* Kg = kbf  + (size_t)bh * SS * KD;
  const short* Vg = vbft + (size_t)bh * KD * SS;
  short* Pw = Ps[w];
  const int bb = bh >> 4, h = bh & 15;

  #pragma unroll 1
  for (int pass = 0; pass < 2; ++pass) {
    const int qb = pass ? (31 - p) : p;
    const int q0 = qb * 64;
    const int nch = qb + 1;

    short8 aq[2];
    {
      const short* qp = qbf + ((size_t)bh * SS + q0 + w * 16) * KD;
      aq[0] = *(const short8*)(qp + (size_t)ln15 * KD + quad * 8);
      aq[1] = *(const short8*)(qp + (size_t)ln15 * KD + 32 + quad * 8);
    }
    f32x4 O[4] = {};                    // [tn], rows quad*4+r
    float mreg[4], lreg[4];             // [r]
    #pragma unroll
    for (int r = 0; r < 4; ++r) { mreg[r] = NEGSENT; lreg[r] = 0.f; }

    stage_kv4(Kg, Vg, 0, Ks[0], Vt[0], tid);   // chunk 0 -> buf 0
    __syncthreads();

    for (int ch = 0; ch < nch; ++ch) {
      const int cur = ch & 1;
      if (ch + 1 < nch)                        // issue next-chunk loads first
        stage_kv4(Kg, Vg, (ch + 1) * 64, Ks[cur ^ 1], Vt[cur ^ 1], tid);
      const short* Kc = Ks[cur];
      const short* Vc = Vt[cur];

      // ---- QK^T: S[16 q][64 k] (actual key order) ----
      f32x4 S[4] = {};
      #pragma unroll
      for (int kt = 0; kt < 2; ++kt) {
        short8 bk[4];
        #pragma unroll
        for (int tn = 0; tn < 4; ++tn)
          bk[tn] = *(const short8*)(Kc + (tn * 16 + ln15) * 64 + ((kt * 32 + quad * 8) ^ rswz));
        #pragma unroll
        for (int tn = 0; tn < 4; ++tn)
          S[tn] = __builtin_amdgcn_mfma_f32_16x16x32_bf16(aq[kt], bk[tn], S[tn], 0, 0, 0);
      }

      // ---- causal mask on the diagonal chunk ----
      if (ch == qb) {
        const int rowl = w * 16 + quad * 4;
        #pragma unroll
        for (int tn = 0; tn < 4; ++tn) {
          const int colk = tn * 16 + ln15;
          #pragma unroll
          for (int r = 0; r < 4; ++r)
            if (colk > rowl + r) S[tn][r] = NEGSENT;
        }
      }

      // ---- cheap per-lane defer-max check (conservative, no shfl) ----
      {
        float lmax = S[0][0];
        #pragma unroll
        for (int tn = 0; tn < 4; ++tn)
          #pragma unroll
          for (int r = 0; r < 4; ++r) lmax = fmaxf(lmax, S[tn][r]);
        const float mmin = fminf(fminf(mreg[0], mreg[1]), fminf(mreg[2], mreg[3]));
        const bool ok = (lmax - mmin) <= THR;
        if (!__all((int)ok)) {                  // rare slow path: full rescale
          #pragma unroll
          for (int r = 0; r < 4; ++r) {
            float mx = fmaxf(fmaxf(fmaxf(S[0][r], S[1][r]), S[2][r]), S[3][r]);
            mx = fmaxf(mx, __shfl_xor(mx, 1, 64));
            mx = fmaxf(mx, __shfl_xor(mx, 2, 64));
            mx = fmaxf(mx, __shfl_xor(mx, 4, 64));
            mx = fmaxf(mx, __shfl_xor(mx, 8, 64));
            const float mn = fmaxf(mreg[r], mx);
            const float al = exp2f((mreg[r] - mn) * SC2);
            mreg[r] = mn;
            lreg[r] *= al;
            O[0][r] *= al; O[1][r] *= al; O[2][r] *= al; O[3][r] *= al;
          }
        }
      }

      // ---- P = exp2(fma(S,SC2,-m*SC2)); l += ...; packed P stores ----
      #pragma unroll
      for (int r = 0; r < 4; ++r) {
        const float mnsc = mreg[r] * SC2;
        const int prow = quad * 4 + r;
        const int rs = (prow & 7) << 3;
        float p0 = exp2f(fmaf(S[0][r], SC2, -mnsc));
        float p1 = exp2f(fmaf(S[1][r], SC2, -mnsc));
        float p2 = exp2f(fmaf(S[2][r], SC2, -mnsc));
        float p3 = exp2f(fmaf(S[3][r], SC2, -mnsc));
        lreg[r] += (p0 + p1) + (p2 + p3);
        *(unsigned int*)(Pw + prow * 64 + ((2 * ln15) ^ rs))      = pk2(p0, p1);
        *(unsigned int*)(Pw + prow * 64 + ((32 + 2 * ln15) ^ rs)) = pk2(p2, p3);
      }
      asm volatile("s_waitcnt lgkmcnt(0)" ::: "memory");  // own P writes landed
      __builtin_amdgcn_sched_barrier(0);                  // rule 18

      // ---- PV: O += P @ V (contraction by position; both PI-ordered) ----
      #pragma unroll
      for (int kt = 0; kt < 2; ++kt) {
        short8 ap = *(const short8*)(Pw + ln15 * 64 + ((kt * 32 + quad * 8) ^ rswz));
        short8 bv[4];
        #pragma unroll
        for (int tn = 0; tn < 4; ++tn)
          bv[tn] = *(const short8*)(Vc + (tn * 16 + ln15) * 64 + ((kt * 32 + quad * 8) ^ rswz));
        #pragma unroll
        for (int tn = 0; tn < 4; ++tn)
          O[tn] = __builtin_amdgcn_mfma_f32_16x16x32_bf16(ap, bv[tn], O[tn], 0, 0, 0);
      }
      __syncthreads();   // next buf staged+visible; prev reads done
    }

    // ---- finalize l and write o token-major (no LDS access) ----
    #pragma unroll
    for (int r = 0; r < 4; ++r) {
      float l = lreg[r];
      l += __shfl_xor(l, 1, 64);
      l += __shfl_xor(l, 2, 64);
      l += __shfl_xor(l, 4, 64);
      l += __shfl_xor(l, 8, 64);
      lreg[r] = 1.f / fmaxf(l, 1e-30f);
    }
    short* ob = obf + ((size_t)bb * SS + q0 + w * 16) * DM + h * KD;
    #pragma unroll
    for (int tn = 0; tn < 4; ++tn)
      #pragma unroll
      for (int r = 0; r < 4; ++r)
        ob[(size_t)(quad * 4 + r) * DM + tn * 16 + ln15] = f2s_hw(O[tn][r] * lreg[r]);
  }
}

// ---------------- legacy fp32 flash attention (fallback, small ws) ----------
__global__ __launch_bounds__(256)
void attn_k(const short* __restrict__ qbf, const float* __restrict__ pres,
            short* __restrict__ obf) {
  __shared__ float Ksf[32][64];
  __shared__ float Vsf[32][64];
  const int bh = blockIdx.x;
  const int q0 = ((int)gridDim.y - 1 - (int)blockIdx.y) * 64;
  const int t  = threadIdx.x;
  const int part = t & 3;
  const int row  = t >> 2;
  const int qr   = q0 + row;
  const int dbase = part * 16;
  const size_t qoff = ((size_t)bh * SS + qr) * KD + dbase;
  float q[16], o[16];
  #pragma unroll
  for (int i = 0; i < 16; ++i) q[i] = us2f((unsigned short)qbf[qoff + i]);
  #pragma unroll
  for (int i = 0; i < 16; ++i) o[i] = 0.f;
  float m = NEGSENT, l = 0.f;
  const float* Kb = pres + (size_t)bh * SS * KD;
  const float* Vb = pres + (size_t)PRES_HALF + (size_t)bh * SS * KD;
  const int nch = (q0 + 64) / 32;
  for (int ch = 0; ch < nch; ++ch) {
    const int kbase = ch * 32;
    __syncthreads();
    {
      const float4* ksrc = (const float4*)(Kb + (size_t)kbase * KD);
      const float4* vsrc = (const float4*)(Vb + (size_t)kbase * KD);
      float4* kdst = (float4*)&Ksf[0][0];
      float4* vdst = (float4*)&Vsf[0][0];
      #pragma unroll
      for (int i = 0; i < 2; ++i) {
        kdst[t + i * 256] = ksrc[t + i * 256];
        vdst[t + i * 256] = vsrc[t + i * 256];
      }
    }
    __syncthreads();
    float sc[32];
    #pragma unroll
    for (int kk = 0; kk < 32; ++kk) {
      float s = 0.f;
      #pragma unroll
      for (int i = 0; i < 16; ++i) s = fmaf(q[i], Ksf[kk][dbase + i], s);
      s += __shfl_xor(s, 1, 64);
      s += __shfl_xor(s, 2, 64);
      sc[kk] = (kbase + kk <= qr) ? s * 0.125f : NEGSENT;
    }
    float mc = sc[0];
    #pragma unroll
    for (int kk = 1; kk < 32; ++kk) mc = fmaxf(mc, sc[kk]);
    const float mn = fmaxf(m, mc);
    const float alpha = __expf(m - mn);
    l *= alpha;
    #pragma unroll
    for (int i = 0; i < 16; ++i) o[i] *= alpha;
    #pragma unroll
    for (int kk = 0; kk < 32; ++kk) {
      const float p = __expf(sc[kk] - mn);
      l += p;
      #pragma unroll
      for (int i = 0; i < 16; ++i) o[i] = fmaf(p, Vsf[kk][dbase + i], o[i]);
    }
    m = mn;
  }
  const float inv = 1.f / fmaxf(l, 1e-30f);
  const int bb = bh >> 4, h = bh & 15;
  const size_t ooff = ((size_t)(bb * SS + qr)) * DM + h * KD + dbase;
  #pragma unroll
  for (int i = 0; i < 16; ++i) obf[ooff + i] = f2s(o[i] * inv);
}

extern "C" void kernel_launch(void* const* d_in, const int* in_sizes, int n_in,
                              void* d_out, int out_size, void* d_ws, size_t ws_size,
                              hipStream_t stream) {
  const float* x      = (const float*)d_in[0];
  const float* w_attn = (const float*)d_in[2];
  const float* b_attn = (const float*)d_in[3];
  const float* w_proj = (const float*)d_in[4];
  const float* b_proj = (const float*)d_in[5];
  float* outf = (float*)d_out;   // fp32: [out0 4M | k 4M | v 4M] elements

  constexpr size_t MB = 1024 * 1024;
  if (ws_size >= 24 * MB) {
    // ---- MFMA-attention path (R12-exact structure) ----
    short* ws0   = (short*)d_ws;
    short* x_bf  = ws0;
    short* o_bf  = ws0;
    short* wat_t = ws0 + (size_t)4 * 1024 * 1024;
    short* wpt_t = ws0 + (size_t)7 * 1024 * 1024;
    short* q_bf  = ws0 + (size_t)8 * 1024 * 1024;
    short* k_bf  = (short*)d_out;
    short* v_bft = k_bf + (size_t)PRES_HALF;

    prep_k<<<8192, 256, 0, stream>>>(x, x_bf, w_attn, wat_t, w_proj, wpt_t);

    qkv_mfma_k<<<dim3(24, 32), 256, 0, stream>>>(x_bf, wat_t, b_attn, q_bf, outf,
                                                 k_bf);

    v_tr_k<<<dim3(BB * NH, SS / 64), 256, 0, stream>>>(
        outf + OUT_ELEMS + PRES_HALF, v_bft);

    attn_mfma9_k<<<dim3(512), 256, 0, stream>>>(q_bf, k_bf, v_bft, o_bf);

    proj_mfma_k<<<dim3(16, 32), 256, 0, stream>>>(o_bf, wpt_t, b_proj, outf);
  } else {
    // ---- legacy fp32-attention fallback ----
    short* x_bf;
    short* q_bf;
    short* wat_t;
    short* wpt_t;
    short* o_bf;
    if (ws_size >= 16 * MB) {
      short* ws = (short*)d_ws;
      x_bf  = (short*)d_out;                 // out0 [0,8MB) dead until proj
      q_bf  = x_bf + OUT_ELEMS;              // out0 [8MB,16MB)
      wat_t = ws;
      wpt_t = wat_t + 3 * DM * DM;
      o_bf  = wat_t + 4 * DM * DM;
    } else {
      x_bf  = (short*)d_out;
      q_bf  = x_bf + OUT_ELEMS;
      wat_t = (short*)d_in[1];
      wpt_t = wat_t + 3 * DM * DM;
      o_bf  = wat_t + 4 * DM * DM;
    }
    prep_k<<<8192, 256, 0, stream>>>(x, x_bf, w_attn, wat_t, w_proj, wpt_t);
    qkv_mfma_k<<<dim3(24, 32), 256, 0, stream>>>(x_bf, wat_t, b_attn, q_bf, outf,
                                                 nullptr);
    attn_k<<<dim3(BB * NH, SS / 64), 256, 0, stream>>>(q_bf, outf + OUT_ELEMS, o_bf);
    proj_mfma_k<<<dim3(16, 32), 256, 0, stream>>>(o_bf, wpt_t, b_proj, outf);
  }
}